// Round 6
// baseline (971.027 us; speedup 1.0000x reference)
//
#include <hip/hip_runtime.h>
#include <math.h>

#define NN 100000
#define DD 128
#define CC 16
#define SS 16
#define EE 3200000
#define KK 64
#define NIT 4
#define CNT_STRIDE 32   // pad class counters 128B apart
#define NB 32           // stage-A tiles per class
#define SLMAX 4096      // max stage-A slice (pow2 >= ceil(NN/NB)=3125)
#define MM (NB * KK)    // stage-B merge size = 2048
#define GRID 256        // persistent blocks == CUs; 1 block/CU guaranteed resident
#define NCHUNK ((NN + 255) / 256)   // 391 candidate chunks
#define INF_STAMP 0x7fffffff

typedef unsigned long long ull;

// barrier state in device globals: zero-init at module load, NOT in poisoned d_ws.
// g_cnt returns to 0 after every barrier; g_gen is monotone (replay-safe: sense
// is read before arrival).
__device__ int g_cnt = 0;
__device__ int g_gen = 0;

__device__ __forceinline__ void gridbar() {
    __syncthreads();
    if (threadIdx.x == 0) {
        int g = __hip_atomic_load(&g_gen, __ATOMIC_RELAXED, __HIP_MEMORY_SCOPE_AGENT);
        int a = __hip_atomic_fetch_add(&g_cnt, 1, __ATOMIC_ACQ_REL, __HIP_MEMORY_SCOPE_AGENT);
        if (a == GRID - 1) {
            __hip_atomic_store(&g_cnt, 0, __ATOMIC_RELAXED, __HIP_MEMORY_SCOPE_AGENT);
            __hip_atomic_fetch_add(&g_gen, 1, __ATOMIC_RELEASE, __HIP_MEMORY_SCOPE_AGENT);
        } else {
            while (__hip_atomic_load(&g_gen, __ATOMIC_ACQUIRE, __HIP_MEMORY_SCOPE_AGENT) == g)
                __builtin_amdgcn_s_sleep(1);
        }
    }
    __syncthreads();
}

// order-preserving double -> uint64 bijection (and exact inverse)
__device__ inline ull ordkey(double d) {
    long long b = __double_as_longlong(d);
    return (b < 0) ? ~(ull)b : ((ull)b | 0x8000000000000000ULL);
}
__device__ inline double keyord(ull u) {
    long long b = (u & 0x8000000000000000ULL)
                    ? (long long)(u & 0x7FFFFFFFFFFFFFFFULL)
                    : (long long)~u;
    return __longlong_as_double(b);
}
// total order: "a earlier than b" == key desc, node asc (== lax.top_k order)
__device__ inline bool gt(ull ka, int na, ull kb, int nb) {
    return (ka > kb) || (ka == kb && na < nb);
}

// in-wave bitonic sort of 64 (key,node) pairs, descending by gt. zero barriers.
__device__ inline void wsort64(ull& k, int& n, int lane) {
    for (int k2 = 2; k2 <= 64; k2 <<= 1) {
        for (int j = k2 >> 1; j; j >>= 1) {
            ull ok = __shfl_xor(k, j, 64);
            int on = __shfl_xor(n, j, 64);
            bool isLow = (lane & j) == 0;
            bool d = (k2 == 64) || ((lane & k2) == 0);
            bool wantMax = (d == isLow);
            if (wantMax == gt(ok, on, k, n)) { k = ok; n = on; }
        }
    }
}
// in-wave bitonic merge (input bitonic), descending by gt
__device__ inline void wmerge64(ull& k, int& n, int lane) {
    for (int j = 32; j; j >>= 1) {
        ull ok = __shfl_xor(k, j, 64);
        int on = __shfl_xor(n, j, 64);
        bool wantMax = (lane & j) == 0;
        if (wantMax == gt(ok, on, k, n)) { k = ok; n = on; }
    }
}

union SMem {
    struct {
        float inp[KK][DD + 1];
        int rowS[KK];
        double q[DD], lg[KK], sr[KK], pre[DD], red[DD];
    } m;                                          // mem step  (~37.4 KB)
    struct {
        int pair[256 * 16];
        short prank[256 * 16];
        double hxnL[CC * 129];
        int lcnt[CC], base[CC], npair;
    } cd;                                         // candidate (~41.2 KB)
    struct { ull ks[SLMAX]; int ns[SLMAX]; } tp;  // top/merge (48 KB)
    struct { int sn[CC * SS]; } sd;               // seeds
};

__global__ __launch_bounds__(256, 1)
void k_all(const float* __restrict__ es, const int* __restrict__ edge,
           const int* __restrict__ seeds, const float* __restrict__ Wm,
           float* __restrict__ out,
           double* __restrict__ inv_norm, int* __restrict__ known,
           unsigned* __restrict__ cate, unsigned* __restrict__ nbr,
           double* __restrict__ hx, double* __restrict__ hxn,
           int* __restrict__ last, int* __restrict__ cnt,
           ull* __restrict__ tkey, int* __restrict__ tnode,
           int* __restrict__ cidx, ull* __restrict__ ckey, int cap) {
    __shared__ SMem sm;
    int tid = threadIdx.x, wave = tid >> 6, lane = tid & 63;

    // ================= phase 0: norms + state init + seeding =================
    if (tid < CC * SS) sm.sd.sn[tid] = seeds[tid];
    __syncthreads();
    for (int n = blockIdx.x * 4 + wave; n < NN; n += GRID * 4) {
        float a = es[(long)n * DD + lane];
        float b = es[(long)n * DD + 64 + lane];
        double p = (double)a * (double)a + (double)b * (double)b;
        for (int o = 32; o > 0; o >>= 1) p += __shfl_xor(p, o, 64);
        unsigned bits = 0;
        #pragma unroll
        for (int j = 0; j < 4; ++j) {
            int idx = lane * 4 + j;
            if (sm.sd.sn[idx] == n) bits |= 1u << (idx >> 4);   // class = idx/SS
        }
        for (int o = 32; o > 0; o >>= 1) bits |= __shfl_xor(bits, o, 64);
        if (lane == 0) {
            inv_norm[n] = 1.0 / (sqrt(p) + 1e-8);
            known[n] = bits ? 0 : INF_STAMP;   // seeds: known since iter 0
            cate[n] = bits;
            nbr[n] = 0;
        }
    }
    gridbar();

    for (int t = 0; t < NIT; ++t) {
        // ============ phase A: memory step (blocks 0..15) || edge pass ============
        if (blockIdx.x < CC) {
            int c = blockIdx.x;
            if (tid == 0) cnt[c * CNT_STRIDE] = 0;
            int k = (t == 0) ? SS : KK;
            if (tid < KK) {
                sm.m.lg[tid] = -1.0e308;
                if (tid < k) sm.m.rowS[tid] = (t == 0) ? seeds[c * SS + tid]
                                                       : last[c * KK + tid];
            }
            __syncthreads();
            for (int i = tid; i < k * DD; i += 256)
                sm.m.inp[i >> 7][i & 127] = es[(long)sm.m.rowS[i >> 7] * DD + (i & 127)];
            __syncthreads();
            if (tid < DD) {
                if (t == 0) {
                    double s = 0;
                    for (int j = 0; j < k; ++j) s += (double)sm.m.inp[j][tid];
                    sm.m.q[tid] = s / (double)k;
                } else {
                    sm.m.q[tid] = hx[c * DD + tid];
                }
            }
            __syncthreads();
            if (tid < k) {
                double s = 0;
                for (int i = 0; i < DD; ++i) s += (double)sm.m.inp[tid][i] * sm.m.q[i];
                sm.m.lg[tid] = s / sqrt((double)DD);
            }
            __syncthreads();
            if (tid < KK) sm.m.sr[tid] = sm.m.lg[tid];
            __syncthreads();
            for (int st = 32; st > 0; st >>= 1) {
                if (tid < st) sm.m.sr[tid] = fmax(sm.m.sr[tid], sm.m.sr[tid + st]);
                __syncthreads();
            }
            double mx = sm.m.sr[0];
            __syncthreads();
            if (tid < KK) {
                double e = (tid < k) ? exp(sm.m.lg[tid] - mx) : 0.0;
                sm.m.lg[tid] = e; sm.m.sr[tid] = e;
            }
            __syncthreads();
            for (int st = 32; st > 0; st >>= 1) {
                if (tid < st) sm.m.sr[tid] += sm.m.sr[tid + st];
                __syncthreads();
            }
            double smm = sm.m.sr[0];
            __syncthreads();
            if (tid < KK) sm.m.lg[tid] /= smm;
            __syncthreads();
            if (tid < DD) {
                double ctx = 0;
                for (int j = 0; j < k; ++j) ctx += sm.m.lg[j] * (double)sm.m.inp[j][tid];
                sm.m.pre[tid] = (t == 0) ? ctx : (ctx + sm.m.q[tid]);
            }
            __syncthreads();
            double h = 0;
            if (tid < DD) {
                for (int i = 0; i < DD; ++i) h += sm.m.pre[i] * (double)Wm[i * DD + tid];
                h = tanh(h);
                sm.m.red[tid] = h * h;
            }
            __syncthreads();
            for (int st = 64; st > 0; st >>= 1) {
                if (tid < st) sm.m.red[tid] += sm.m.red[tid + st];
                __syncthreads();
            }
            if (tid < DD) {
                double inv = 1.0 / (sqrt(sm.m.red[0]) + 1e-8);
                hx[c * DD + tid] = h;
                hxn[c * DD + tid] = h * inv;
                out[2 * NIT * CC * KK + t * CC * DD + c * DD + tid] = (float)h;  // hxes
            }
        } else {
            const int stripe = (EE + (GRID - CC) - 1) / (GRID - CC);   // 13334
            long e0 = (long)(blockIdx.x - CC) * stripe;
            long e1 = e0 + stripe; if (e1 > EE) e1 = EE;
            for (long e = e0 + tid; e < e1; e += 256) {
                int s = edge[e];
                unsigned mm = cate[s];
                if (mm) atomicOr(&nbr[edge[EE + e]], mm);
            }
        }
        gridbar();

        // ================ phase B: candidate scoring (all blocks) ================
        for (int i = tid; i < CC * DD; i += 256)
            sm.cd.hxnL[(i >> 7) * 129 + (i & 127)] = hxn[i];
        __syncthreads();
        for (int vb = blockIdx.x; vb < NCHUNK; vb += GRID) {
            if (tid < CC) sm.cd.lcnt[tid] = 0;
            if (tid == 0) sm.cd.npair = 0;
            __syncthreads();
            int n = vb * 256 + tid;
            unsigned m = 0;
            if (n < NN && known[n] > t) m = nbr[n];   // stamp > t <=> unknown at iter t
            while (m) {
                int c = __ffs(m) - 1;
                m &= m - 1;
                int r = atomicAdd(&sm.cd.lcnt[c], 1);
                int p = atomicAdd(&sm.cd.npair, 1);
                sm.cd.pair[p] = (n << 4) | c;
                sm.cd.prank[p] = (short)r;
            }
            __syncthreads();
            if (tid < CC && sm.cd.lcnt[tid] > 0)
                sm.cd.base[tid] = atomicAdd(&cnt[tid * CNT_STRIDE], sm.cd.lcnt[tid]);
            __syncthreads();
            int np = sm.cd.npair;
            for (int t2 = tid; t2 < np; t2 += 256) {
                int pk = sm.cd.pair[t2];
                int nn = pk >> 4, c = pk & 15;
                const float4* row = (const float4*)(es + (long)nn * DD);
                const double* h = &sm.cd.hxnL[c * 129];
                double s = 0;
                #pragma unroll
                for (int i = 0; i < 32; ++i) {
                    float4 v = row[i];
                    s += (double)v.x * h[4 * i + 0] + (double)v.y * h[4 * i + 1]
                       + (double)v.z * h[4 * i + 2] + (double)v.w * h[4 * i + 3];
                }
                int pos = sm.cd.base[c] + (int)sm.cd.prank[t2];
                if (pos < cap) {
                    cidx[(long)c * cap + pos] = nn;
                    ckey[(long)c * cap + pos] = ordkey(s * inv_norm[nn]);
                }
            }
            __syncthreads();
        }
        gridbar();

        // ========== phase C: per-slice top-64 (512 virtual tiles, 2/block) ==========
        for (int vt = blockIdx.x; vt < CC * NB; vt += GRID) {
            int c = vt / NB, b = vt % NB;
            int count = min(cnt[c * CNT_STRIDE], cap);
            int per = (count + NB - 1) / NB;
            int start = b * per;
            int m2 = min(per, count - start);
            int sl = 64;
            while (sl < per) sl <<= 1;
            int nruns = sl >> 6;
            __syncthreads();   // protect LDS reuse across virtual tiles / phases
            for (int r = wave; r < nruns; r += 4) {
                int i = (r << 6) + lane;
                ull k; int n;
                if (i < m2) { k = ckey[(long)c * cap + start + i];
                              n = cidx[(long)c * cap + start + i]; }
                else        { k = 0ULL; n = 0x7FFFFFFF; }
                wsort64(k, n, lane);
                sm.tp.ks[i] = k; sm.tp.ns[i] = n;
            }
            __syncthreads();
            for (int step = 1; step < nruns; step <<= 1) {
                int npair2 = nruns / (2 * step);
                for (int pr = wave; pr < npair2; pr += 4) {
                    int ra = pr * 2 * step, rb = ra + step;
                    ull ka = sm.tp.ks[(ra << 6) + lane];       int na = sm.tp.ns[(ra << 6) + lane];
                    ull kb = sm.tp.ks[(rb << 6) + 63 - lane];  int nb2 = sm.tp.ns[(rb << 6) + 63 - lane];
                    if (gt(kb, nb2, ka, na)) { ka = kb; na = nb2; }   // bitonic split
                    wmerge64(ka, na, lane);
                    sm.tp.ks[(ra << 6) + lane] = ka; sm.tp.ns[(ra << 6) + lane] = na;
                }
                __syncthreads();
            }
            if (tid < KK) {
                tkey[(long)c * MM + b * KK + tid] = sm.tp.ks[tid];
                tnode[(long)c * MM + b * KK + tid] = sm.tp.ns[tid];
            }
        }
        gridbar();

        // ===== phase D: merge 32 runs -> top-64, apply updates + outputs (blocks 0..15) =====
        if (blockIdx.x < CC) {
            int c = blockIdx.x;
            for (int i = tid; i < MM; i += 256) {
                sm.tp.ks[i] = tkey[(long)c * MM + i];
                sm.tp.ns[i] = tnode[(long)c * MM + i];
            }
            __syncthreads();
            for (int step = 1; step < NB; step <<= 1) {
                int npair2 = NB / (2 * step);
                for (int pr = wave; pr < npair2; pr += 4) {
                    int ra = pr * 2 * step, rb = ra + step;
                    ull ka = sm.tp.ks[(ra << 6) + lane];       int na = sm.tp.ns[(ra << 6) + lane];
                    ull kb = sm.tp.ks[(rb << 6) + 63 - lane];  int nb2 = sm.tp.ns[(rb << 6) + 63 - lane];
                    if (gt(kb, nb2, ka, na)) { ka = kb; na = nb2; }
                    wmerge64(ka, na, lane);
                    sm.tp.ks[(ra << 6) + lane] = ka; sm.tp.ns[(ra << 6) + lane] = na;
                }
                __syncthreads();
            }
            int count = min(cnt[c * CNT_STRIDE], cap);
            int nsel = min(count, KK);
            if (tid < KK && tid < nsel) {
                int n = sm.tp.ns[tid];
                out[t * CC * KK + c * KK + tid] = (float)keyord(sm.tp.ks[tid]);   // outs
                out[NIT * CC * KK + t * CC * KK + c * KK + tid] = (float)n;       // exps
                last[c * KK + tid] = n;
                known[n] = t + 1;            // stamp invisible to this iteration's tests
                atomicOr(&cate[n], 1u << c);
            }
            // fill path: lowest-index invalid nodes, prob=-1e9. stamp test sees only
            // pre-iteration state -> race-free vs concurrent t+1 stamps (== reference).
            if (tid == 0 && nsel < KK) {
                int r = nsel;
                for (int n = 0; n < NN && r < KK; ++n) {
                    bool valid = ((nbr[n] >> c) & 1u) && (known[n] > t);
                    if (!valid) {
                        out[t * CC * KK + c * KK + r] = -1e9f;
                        out[NIT * CC * KK + t * CC * KK + c * KK + r] = (float)n;
                        last[c * KK + r] = n;
                        known[n] = t + 1;
                        atomicOr(&cate[n], 1u << c);
                        ++r;
                    }
                }
            }
        }
        gridbar();
    }
}

// -------------------- host launcher --------------------

extern "C" void kernel_launch(void* const* d_in, const int* in_sizes, int n_in,
                              void* d_out, int out_size, void* d_ws, size_t ws_size,
                              hipStream_t stream) {
    const float* es    = (const float*)d_in[0];
    const int*   edge  = (const int*)d_in[1];
    const int*   seeds = (const int*)d_in[2];
    const float* W     = (const float*)d_in[3];
    float* out = (float*)d_out;

    char* p = (char*)d_ws;
    auto alloc = [&](size_t bytes) -> char* {
        char* r = p;
        p += (bytes + 255) & ~(size_t)255;
        return r;
    };
    double*   inv_norm = (double*)alloc((size_t)NN * 8);
    int*      known    = (int*)alloc((size_t)NN * 4);
    unsigned* cate     = (unsigned*)alloc((size_t)NN * 4);
    unsigned* nbr      = (unsigned*)alloc((size_t)NN * 4);
    double*   hx       = (double*)alloc(CC * DD * 8);
    double*   hxn      = (double*)alloc(CC * DD * 8);
    int*      last     = (int*)alloc(CC * KK * 4);
    int*      cnt      = (int*)alloc(CC * CNT_STRIDE * 4);
    ull*      tkey     = (ull*)alloc((size_t)CC * MM * 8);
    int*      tnode    = (int*)alloc((size_t)CC * MM * 4);
    size_t used = (size_t)(p - (char*)d_ws);
    size_t rem = (ws_size > used + 8192) ? (ws_size - used - 8192) : 0;
    long capl = (long)(rem / (CC * 12));
    if (capl > NN) capl = NN;
    if (capl < 1) capl = 1;
    int cap = (int)capl;
    int*    cidx = (int*)alloc((size_t)CC * cap * 4);
    ull*    ckey = (ull*)alloc((size_t)CC * cap * 8);

    k_all<<<GRID, 256, 0, stream>>>(es, edge, seeds, W, out,
                                    inv_norm, known, cate, nbr, hx, hxn,
                                    last, cnt, tkey, tnode, cidx, ckey, cap);
}